// Round 5
// baseline (1606.999 us; speedup 1.0000x reference)
//
#include <hip/hip_runtime.h>
#include <stdint.h>

#define N_UPDATE 3
#define HD 32
#define FN 16

typedef unsigned short u16;
typedef __bf16 bf16x8 __attribute__((ext_vector_type(8)));
typedef float f32x4 __attribute__((ext_vector_type(4)));

__device__ __forceinline__ float bf2f(u16 u) {
  union { uint32_t i; float f; } v; v.i = ((uint32_t)u) << 16; return v.f;
}
__device__ __forceinline__ u16 f2bf(float f) {
  union { uint32_t i; float f; } v; v.f = f;
  uint32_t x = v.i;
  return (u16)((x + 0x7fffu + ((x >> 16) & 1u)) >> 16);  // RNE
}

union frag16 { uint4 v; bf16x8 b; u16 s[8]; };

__global__ void k_zero_f(float* __restrict__ p, int n) {
  int i = blockIdx.x * blockDim.x + threadIdx.x;
  if (i < n) p[i] = 0.f;
}
__global__ void k_zero_i(int* __restrict__ p, int n) {
  int i = blockIdx.x * blockDim.x + threadIdx.x;
  if (i < n) p[i] = 0;
}

// ---------------- sort by src: histogram
__global__ void k_hist(const int* __restrict__ eidx, int* __restrict__ cnt, int E) {
  int e = blockIdx.x * blockDim.x + threadIdx.x;
  if (e >= E) return;
  atomicAdd(&cnt[eidx[2 * e]], 1);
}

// ---------------- single-block exclusive scan over cnt -> ptr (N elements)
__global__ __launch_bounds__(1024) void k_scan(const int* __restrict__ cnt,
                                               int* __restrict__ ptr, int N) {
  __shared__ int sums[1024];
  int chunk = (N + 1023) / 1024;
  int beg = threadIdx.x * chunk;
  int end = beg + chunk; if (end > N) end = N;
  int s = 0;
  for (int i = beg; i < end; i++) s += cnt[i];
  sums[threadIdx.x] = s;
  __syncthreads();
  for (int off = 1; off < 1024; off <<= 1) {
    int v = (threadIdx.x >= off) ? sums[threadIdx.x - off] : 0;
    __syncthreads();
    sums[threadIdx.x] += v;
    __syncthreads();
  }
  int run = (threadIdx.x == 0) ? 0 : sums[threadIdx.x - 1];
  for (int i = beg; i < end; i++) { ptr[i] = run; run += cnt[i]; }
}

// ---------------- scatter: sorted position per edge
__global__ void k_scatter(const int* __restrict__ eidx, int* __restrict__ ptr,
                          int* __restrict__ se_src, int* __restrict__ se_dst,
                          int* __restrict__ invp, int E) {
  int e = blockIdx.x * blockDim.x + threadIdx.x;
  if (e >= E) return;
  int2 sd = ((const int2*)eidx)[e];
  int pos = atomicAdd(&ptr[sd.x], 1);
  se_src[pos] = sd.x;
  se_dst[pos] = sd.y;
  invp[e] = pos;
}

// ---------------- Bf[t][lane]: MFMA B-fragments, 128 tiles (2 passes x 64).
// pass p, tile t2, col c: j2=t2*16+c, o_l=j2>>6, k=j2&63, o=p*16+o_l
// B[h][j2] = Wm2[k*1024 + h*32 + o]
__global__ void k_prep_bf(const float* __restrict__ Wm2, uint4* __restrict__ Bf) {
  int t = blockIdx.x;       // 128
  int lane = threadIdx.x;   // 64
  int col = lane & 15;
  int hg = lane >> 4;
  int p = t >> 6;
  int t2 = t & 63;
  int j2 = t2 * 16 + col;
  int o = p * 16 + (j2 >> 6);
  int k = j2 & 63;
  frag16 f;
#pragma unroll
  for (int jj = 0; jj < 8; jj++) {
    int h = hg * 8 + jj;
    f.s[jj] = f2bf(Wm2[k * 1024 + h * 32 + o]);
  }
  Bf[t * 64 + lane] = f.v;
}

// ---------------- h0 init
__global__ void k_init_h(const float* __restrict__ x, float* __restrict__ h, int N) {
  int idx = blockIdx.x * blockDim.x + threadIdx.x;
  if (idx >= N * HD) return;
  int n = idx >> 5, c = idx & 31;
  h[idx] = (c < FN) ? x[n * FN + c] : 0.f;
}

// ---------------- edge MLP -> ee bf16 [E][64], written at sorted position invp[e]
__global__ __launch_bounds__(256) void k_edge_mlp(
    const float* __restrict__ ea,
    const float* __restrict__ Wm0, const float* __restrict__ bm0,
    const float* __restrict__ Wm1, const float* __restrict__ bm1,
    const int* __restrict__ invp, u16* __restrict__ ee, int E) {
  int e = blockIdx.x * blockDim.x + threadIdx.x;
  if (e >= E) return;
  float a[16];
  {
    const float4* p = (const float4*)(ea + (size_t)e * 16);
    float4 v0 = p[0], v1 = p[1], v2 = p[2], v3 = p[3];
    a[0]=v0.x; a[1]=v0.y; a[2]=v0.z; a[3]=v0.w;
    a[4]=v1.x; a[5]=v1.y; a[6]=v1.z; a[7]=v1.w;
    a[8]=v2.x; a[9]=v2.y; a[10]=v2.z; a[11]=v2.w;
    a[12]=v3.x; a[13]=v3.y; a[14]=v3.z; a[15]=v3.w;
  }
  float t0[64];
#pragma unroll
  for (int j = 0; j < 64; j++) t0[j] = bm0[j];
#pragma unroll
  for (int k = 0; k < 16; k++) {
    float av = a[k];
#pragma unroll
    for (int j = 0; j < 64; j++) t0[j] = fmaf(av, Wm0[k * 64 + j], t0[j]);
  }
#pragma unroll
  for (int j = 0; j < 64; j++) t0[j] = fmaxf(t0[j], 0.f);

  u16* dst = ee + (size_t)invp[e] * 64;
#pragma unroll
  for (int half = 0; half < 2; half++) {
    float t1[32];
#pragma unroll
    for (int j = 0; j < 32; j++) t1[j] = bm1[half * 32 + j];
#pragma unroll
    for (int k = 0; k < 64; k++) {
      float tv = t0[k];
#pragma unroll
      for (int j = 0; j < 32; j++) t1[j] = fmaf(tv, Wm1[k * 64 + half * 32 + j], t1[j]);
    }
    unsigned int out[16];
#pragma unroll
    for (int j = 0; j < 16; j++) {
      u16 lo = f2bf(fmaxf(t1[2 * j], 0.f));
      u16 hi = f2bf(fmaxf(t1[2 * j + 1], 0.f));
      out[j] = (unsigned int)lo | ((unsigned int)hi << 16);
    }
    uint4* op = (uint4*)(dst + half * 32);
#pragma unroll
    for (int q = 0; q < 4; q++) {
      uint4 w; w.x = out[q*4+0]; w.y = out[q*4+1]; w.z = out[q*4+2]; w.w = out[q*4+3];
      op[q] = w;
    }
  }
}

// ---------------- G GEMM pass p: Gb[n][j2], j2 = o_l*64+k (o = p*16+o_l)
__global__ __launch_bounds__(256) void k_gemm_G(
    const float* __restrict__ h, const uint4* __restrict__ Bf,
    u16* __restrict__ Gb, int N, int p) {
  int wave = threadIdx.x >> 6;
  int lane = threadIdx.x & 63;
  int jt = blockIdx.y * 4 + wave;   // [0,64)
  int n0 = blockIdx.x * 16;
  int row = lane & 15;
  int kg = lane >> 4;

  int nr = n0 + row; if (nr > N - 1) nr = N - 1;
  const float* hr = h + (size_t)nr * HD + kg * 8;
  float4 f0 = *(const float4*)hr;
  float4 f1 = *(const float4*)(hr + 4);
  frag16 a;
  a.s[0] = f2bf(f0.x); a.s[1] = f2bf(f0.y); a.s[2] = f2bf(f0.z); a.s[3] = f2bf(f0.w);
  a.s[4] = f2bf(f1.x); a.s[5] = f2bf(f1.y); a.s[6] = f2bf(f1.z); a.s[7] = f2bf(f1.w);

  frag16 b; b.v = Bf[(p * 64 + jt) * 64 + lane];

  f32x4 acc = {0.f, 0.f, 0.f, 0.f};
  acc = __builtin_amdgcn_mfma_f32_16x16x32_bf16(a.b, b.b, acc, 0, 0, 0);

  int j2 = jt * 16 + row;
#pragma unroll
  for (int r = 0; r < 4; r++) {
    int n = n0 + kg * 4 + r;
    if (n < N) Gb[(size_t)n * 1024 + j2] = f2bf(acc[r]);
  }
}

// ---------------- msg pass p: 16 lanes per sorted edge, lane o_l; o = p*16+o_l
// acc = sum_k ee[e][k]*Gb[src][o_l*64+k] + sum_hh h[src][hh]*bm2[hh*32+o]
__global__ __launch_bounds__(256) void k_msg(
    const u16* __restrict__ Gb, const float* __restrict__ h,
    const float* __restrict__ bm2, const u16* __restrict__ ee,
    const int* __restrict__ se_src, const int* __restrict__ se_dst,
    float* __restrict__ agg, int E, int p) {
  int t = blockIdx.x * blockDim.x + threadIdx.x;
  int e = t >> 4;
  int o_l = t & 15;
  if (e >= E) return;
  int src = se_src[e];
  int dst = se_dst[e];
  int o = p * 16 + o_l;

  // bias (bm2) term via width-16 shuffles
  float hv0 = h[(size_t)src * HD + o_l];
  float hv1 = h[(size_t)src * HD + 16 + o_l];
  float acc = 0.f;
#pragma unroll
  for (int hh = 0; hh < 16; hh++) {
    acc = fmaf(__shfl(hv0, hh, 16), bm2[hh * 32 + o], acc);
    acc = fmaf(__shfl(hv1, hh, 16), bm2[(hh + 16) * 32 + o], acc);
  }

  const uint4* ep = (const uint4*)(ee + (size_t)e * 64);
  const uint4* gp = (const uint4*)(Gb + ((size_t)src * 16 + o_l) * 64);
  frag16 eu[8], gu[8];
#pragma unroll
  for (int q = 0; q < 8; q++) { eu[q].v = ep[q]; gu[q].v = gp[q]; }
#pragma unroll
  for (int k = 0; k < 64; k++) {
    acc = fmaf(bf2f(eu[k >> 3].s[k & 7]), bf2f(gu[k >> 3].s[k & 7]), acc);
  }
  atomicAdd(&agg[(size_t)dst * HD + o], acc);
}

// ---------------- node update (also re-zeroes agg for next iteration)
__global__ __launch_bounds__(256) void k_update(
    const float* __restrict__ h, float* __restrict__ agg,
    const float* __restrict__ root, const float* __restrict__ bias,
    float* __restrict__ hn, int N) {
  int t = blockIdx.x * blockDim.x + threadIdx.x;
  int n = t >> 5, o = t & 31;
  if (n >= N) return;
  float hv = h[(size_t)n * HD + o];
  float acc = bias[o] + agg[(size_t)n * HD + o];
  agg[(size_t)n * HD + o] = 0.f;
#pragma unroll
  for (int k = 0; k < 32; k++)
    acc = fmaf(__shfl(hv, k, 32), root[k * HD + o], acc);
  hn[(size_t)n * HD + o] = acc;
}

// ---------------- readout
__global__ __launch_bounds__(256) void k_readout(
    const float* __restrict__ h, const float* __restrict__ x,
    const float* __restrict__ Wi0, const float* __restrict__ bi0,
    const float* __restrict__ Wi1, const float* __restrict__ bi1,
    const float* __restrict__ Wj0, const float* __restrict__ bj0,
    const float* __restrict__ Wj1, const float* __restrict__ bj1,
    float* __restrict__ partial, int N) {
  int wid = threadIdx.x >> 6;
  int lane = threadIdx.x & 63;
  int n = blockIdx.x * 4 + wid;
  __shared__ float sred[4];
  float contrib = 0.f;
  if (n < N) {
    float uv;
    if (lane < 32) uv = h[(size_t)n * HD + lane];
    else if (lane < 48) uv = x[(size_t)n * FN + lane - 32];
    else uv = 0.f;

    float g1a = bi0[lane], g1b = bi0[lane + 64];
#pragma unroll
    for (int k = 0; k < 64; k++) {
      float u = __shfl(uv, k, 64);
      g1a = fmaf(u, Wi0[k * 128 + lane], g1a);
      g1b = fmaf(u, Wi0[k * 128 + lane + 64], g1b);
    }
    g1a = fmaxf(g1a, 0.f); g1b = fmaxf(g1b, 0.f);
    float gp = g1a * Wi1[lane] + g1b * Wi1[lane + 64];

    float v1a = bj0[lane], v1b = bj0[lane + 64];
#pragma unroll
    for (int k = 0; k < 32; k++) {
      float hk = __shfl(uv, k, 64);
      v1a = fmaf(hk, Wj0[k * 128 + lane], v1a);
      v1b = fmaf(hk, Wj0[k * 128 + lane + 64], v1b);
    }
    v1a = fmaxf(v1a, 0.f); v1b = fmaxf(v1b, 0.f);
    float vp = v1a * Wj1[lane] + v1b * Wj1[lane + 64];

#pragma unroll
    for (int s = 32; s; s >>= 1) {
      gp += __shfl_xor(gp, s, 64);
      vp += __shfl_xor(vp, s, 64);
    }
    float gate = 1.f / (1.f + __expf(-(gp + bi1[0])));
    float val = vp + bj1[0];
    contrib = gate * val;
  }
  if (lane == 0) sred[wid] = contrib;
  __syncthreads();
  if (threadIdx.x == 0) partial[blockIdx.x] = sred[0] + sred[1] + sred[2] + sred[3];
}

__global__ void k_final(const float* __restrict__ partial, float* __restrict__ out, int P) {
  __shared__ float sm[256];
  float s = 0.f;
  for (int i = threadIdx.x; i < P; i += 256) s += partial[i];
  sm[threadIdx.x] = s;
  __syncthreads();
  for (int st = 128; st; st >>= 1) {
    if ((int)threadIdx.x < st) sm[threadIdx.x] += sm[threadIdx.x + st];
    __syncthreads();
  }
  if (threadIdx.x == 0) out[0] = sm[0];
}

extern "C" void kernel_launch(void* const* d_in, const int* in_sizes, int n_in,
                              void* d_out, int out_size, void* d_ws, size_t ws_size,
                              hipStream_t stream) {
  const float* x    = (const float*)d_in[0];
  const int*   eidx = (const int*)d_in[1];
  const float* ea   = (const float*)d_in[2];
  const float* Wm0  = (const float*)d_in[3];
  const float* bm0  = (const float*)d_in[4];
  const float* Wm1  = (const float*)d_in[5];
  const float* bm1  = (const float*)d_in[6];
  const float* Wm2  = (const float*)d_in[7];
  const float* bm2  = (const float*)d_in[8];
  const float* root = (const float*)d_in[9];
  const float* bias = (const float*)d_in[10];
  const float* Wi0  = (const float*)d_in[11];
  const float* bi0  = (const float*)d_in[12];
  const float* Wi1  = (const float*)d_in[13];
  const float* bi1  = (const float*)d_in[14];
  const float* Wj0  = (const float*)d_in[15];
  const float* bj0  = (const float*)d_in[16];
  const float* Wj1  = (const float*)d_in[17];
  const float* bj1  = (const float*)d_in[18];

  int N = in_sizes[0] / FN;
  int E = in_sizes[1] / 2;
  int nb = (N + 3) / 4;

  auto al = [](size_t b) { return (b + 255) & ~(size_t)255; };
  size_t need = al((size_t)N * 1024 * 2) + al((size_t)E * 64 * 2) +
                al(128 * 64 * sizeof(uint4)) + 3 * al((size_t)N * HD * 4) +
                2 * al((size_t)N * 4) + 3 * al((size_t)E * 4) + al((size_t)nb * 4);
  if (need > ws_size) return;  // beacon: workspace too small

  char* ws = (char*)d_ws;
  size_t off = 0;
  auto alloc = [&](size_t bytes) { void* p = ws + off; off += al(bytes); return p; };
  u16*   Gb      = (u16*)alloc((size_t)N * 1024 * 2);    // 102.4 MB
  u16*   ee      = (u16*)alloc((size_t)E * 64 * 2);      // 51.2 MB
  uint4* Bf      = (uint4*)alloc(128 * 64 * sizeof(uint4));
  float* hA      = (float*)alloc((size_t)N * HD * 4);
  float* hB      = (float*)alloc((size_t)N * HD * 4);
  float* agg     = (float*)alloc((size_t)N * HD * 4);
  int*   cnt     = (int*)alloc((size_t)N * 4);
  int*   ptr     = (int*)alloc((size_t)N * 4);
  int*   se_src  = (int*)alloc((size_t)E * 4);
  int*   se_dst  = (int*)alloc((size_t)E * 4);
  int*   invp    = (int*)alloc((size_t)E * 4);
  float* partial = (float*)alloc((size_t)nb * 4);

  int mt = (N + 15) / 16;
  int ng = (N * HD + 255) / 256;
  int eg = (E + 255) / 256;

  // ---- sort edges by src (once) ----
  hipLaunchKernelGGL(k_zero_i, dim3((N + 255) / 256), dim3(256), 0, stream, cnt, N);
  hipLaunchKernelGGL(k_hist, dim3(eg), dim3(256), 0, stream, eidx, cnt, E);
  hipLaunchKernelGGL(k_scan, dim3(1), dim3(1024), 0, stream, cnt, ptr, N);
  hipLaunchKernelGGL(k_scatter, dim3(eg), dim3(256), 0, stream, eidx, ptr, se_src, se_dst, invp, E);

  hipLaunchKernelGGL(k_prep_bf, dim3(128), dim3(64), 0, stream, Wm2, Bf);
  hipLaunchKernelGGL(k_init_h, dim3(ng), dim3(256), 0, stream, x, hA, N);
  hipLaunchKernelGGL(k_edge_mlp, dim3(eg), dim3(256), 0, stream,
                     ea, Wm0, bm0, Wm1, bm1, invp, ee, E);
  hipLaunchKernelGGL(k_zero_f, dim3(ng), dim3(256), 0, stream, agg, N * HD);

  float* hc = hA; float* hn = hB;
  for (int it = 0; it < N_UPDATE; it++) {
    for (int p = 0; p < 2; p++) {
      hipLaunchKernelGGL(k_gemm_G, dim3(mt, 16), dim3(256), 0, stream, hc, Bf, Gb, N, p);
      hipLaunchKernelGGL(k_msg, dim3(((size_t)E * 16 + 255) / 256), dim3(256), 0, stream,
                         Gb, hc, bm2, ee, se_src, se_dst, agg, E, p);
    }
    hipLaunchKernelGGL(k_update, dim3(ng), dim3(256), 0, stream,
                       hc, agg, root, bias, hn, N);
    float* tmp = hc; hc = hn; hn = tmp;
  }

  hipLaunchKernelGGL(k_readout, dim3(nb), dim3(256), 0, stream,
                     hc, x, Wi0, bi0, Wi1, bi1, Wj0, bj0, Wj1, bj1, partial, N);
  hipLaunchKernelGGL(k_final, dim3(1), dim3(256), 0, stream, partial, (float*)d_out, nb);
}